// Round 11
// baseline (959.205 us; speedup 1.0000x reference)
//
#include <hip/hip_runtime.h>
#include <hip/hip_bf16.h>

#define B_   256
#define T_   512
#define H_   128
#define G3_  384

// ---- tiled GEMM config ----
#define TM   128
#define TN   128
#define TK   32
#define LDA  132

// log2(e) and 2*log2(e): gate pre-activations are pre-scaled so the serial
// recurrence uses raw v_exp_f32 (2^x) with no per-call *1.4427 mul.
#define LOG2E_F  1.4426950408889634f
#define LOG2E2_F 2.8853900817779268f

typedef float v4f __attribute__((ext_vector_type(4)));
typedef float v2f __attribute__((ext_vector_type(2)));

__device__ __forceinline__ float fast_rcp(float x) {
    return __builtin_amdgcn_rcpf(x);
}
__device__ __forceinline__ float exp2_raw(float x) {
    return __builtin_amdgcn_exp2f(x);   // v_exp_f32: 2^x
}

// Packed FMA, all operands arch-VGPR (R15-proven; VOP3P cannot take AGPR
// sources on gfx950 — R17 compile falsifier).
__device__ __forceinline__ void pk_fma(v2f& acc, v2f a, v2f b) {
    asm("v_pk_fma_f32 %0, %1, %2, %0" : "+v"(acc) : "v"(a), "v"(b));
}

// Butterfly sum over each aligned 4-lane quad, pure DPP, result on ALL lanes.
__device__ __forceinline__ float bfly_fold4(float v) {
    int x;
    x = __builtin_amdgcn_update_dpp(0, __float_as_int(v), 0x0B1, 0xF, 0xF, true);
    v += __int_as_float(x);   // xor 1
    x = __builtin_amdgcn_update_dpp(0, __float_as_int(v), 0x04E, 0xF, 0xF, true);
    v += __int_as_float(x);   // xor 2
    return v;
}

// Butterfly sum over each aligned 8-lane group (R8/R13-proven), all lanes.
__device__ __forceinline__ float bfly_fold8(float v) {
    int x;
    x = __builtin_amdgcn_update_dpp(0, __float_as_int(v), 0x0B1, 0xF, 0xF, true);
    v += __int_as_float(x);   // xor 1
    x = __builtin_amdgcn_update_dpp(0, __float_as_int(v), 0x04E, 0xF, 0xF, true);
    v += __int_as_float(x);   // xor 2
    x = __builtin_amdgcn_update_dpp(0, __float_as_int(v), 0x141, 0xF, 0xF, true);
    v += __int_as_float(x);   // half mirror within the 8-group's quads
    return v;
}

// ---------------------------------------------------------------------------
// gx GEMM (R2 structure; R14 bias2 fold; R15 exp2 pre-scale epilogue)
// ---------------------------------------------------------------------------
template<bool GATHER>
__global__ __launch_bounds__(256, 2)
void gx_gemm(const float* __restrict__ X,
             const int*   __restrict__ idx,
             const float* __restrict__ emb,
             const float* __restrict__ W,     // [384,128] row-major
             const float* __restrict__ bias,  // [384]  (b_ih)
             const float* __restrict__ bias2, // [384]  (b_hh; only n<256 used)
             float*       __restrict__ gx)    // [M,384]
{
    __shared__ __align__(16) float As[2][TK][LDA];
    __shared__ __align__(16) float Bs[2][TK][LDA];

    const int tid = threadIdx.x;
    const int tn  = tid & 15;
    const int tm  = tid >> 4;
    const int n0  = blockIdx.x * TN;
    const int m0  = blockIdx.y * TM;

    const int q  = tid & 7;
    const float* rowA[4];
    const float* rowB[4];
#pragma unroll
    for (int s = 0; s < 4; s++) {
        const int r = (tid >> 3) + 32 * s;
        rowA[s] = GATHER ? (emb + (size_t)idx[m0 + r] * H_)
                         : (X + (size_t)(m0 + r) * H_);
        rowB[s] = W + (size_t)(n0 + r) * H_;
    }

    float4 stA[4], stB[4];
    auto load_chunk = [&](int kc) {
#pragma unroll
        for (int s = 0; s < 4; s++) {
            stA[s] = *(const float4*)(rowA[s] + kc + q * 4);
            stB[s] = *(const float4*)(rowB[s] + kc + q * 4);
        }
    };
    auto store_chunk = [&](int buf) {
#pragma unroll
        for (int s = 0; s < 4; s++) {
            const int r = (tid >> 3) + 32 * s;
#pragma unroll
            for (int d = 0; d < 4; d++) {
                As[buf][q * 4 + d][r] = ((const float*)&stA[s])[d];
                Bs[buf][q * 4 + d][r] = ((const float*)&stB[s])[d];
            }
        }
    };

    float4 acc[2][2][4];
#pragma unroll
    for (int a = 0; a < 2; a++)
#pragma unroll
        for (int b = 0; b < 2; b++)
#pragma unroll
            for (int c = 0; c < 4; c++) acc[a][b][c] = make_float4(0.f, 0.f, 0.f, 0.f);

    load_chunk(0);
    store_chunk(0);
    __syncthreads();

    for (int c = 0; c < 4; c++) {
        if (c < 3) load_chunk((c + 1) * TK);
        const int buf = c & 1;
#pragma unroll 4
        for (int k = 0; k < TK; k++) {
            float4 a0 = *(const float4*)&As[buf][k][tm * 4];
            float4 a1 = *(const float4*)&As[buf][k][64 + tm * 4];
            float4 b0 = *(const float4*)&Bs[buf][k][tn * 4];
            float4 b1 = *(const float4*)&Bs[buf][k][64 + tn * 4];
            float4 av[2] = {a0, a1}, bv[2] = {b0, b1};
#pragma unroll
            for (int mg = 0; mg < 2; mg++)
#pragma unroll
                for (int mi = 0; mi < 4; mi++) {
                    const float am = ((const float*)&av[mg])[mi];
#pragma unroll
                    for (int ng = 0; ng < 2; ng++) {
                        acc[mg][ng][mi].x = fmaf(am, bv[ng].x, acc[mg][ng][mi].x);
                        acc[mg][ng][mi].y = fmaf(am, bv[ng].y, acc[mg][ng][mi].y);
                        acc[mg][ng][mi].z = fmaf(am, bv[ng].z, acc[mg][ng][mi].z);
                        acc[mg][ng][mi].w = fmaf(am, bv[ng].w, acc[mg][ng][mi].w);
                    }
                }
        }
        if (c < 3) {
            store_chunk(buf ^ 1);
            __syncthreads();
        }
    }

    float4 bb0 = *(const float4*)(bias + n0 + tn * 4);
    float4 bb1 = *(const float4*)(bias + n0 + 64 + tn * 4);
    if (n0 < 2 * H_) {   // r/z gate regions: fold hidden bias in here (uniform)
        const float4 c0 = *(const float4*)(bias2 + n0 + tn * 4);
        const float4 c1 = *(const float4*)(bias2 + n0 + 64 + tn * 4);
        bb0.x += c0.x; bb0.y += c0.y; bb0.z += c0.z; bb0.w += c0.w;
        bb1.x += c1.x; bb1.y += c1.y; bb1.z += c1.z; bb1.w += c1.w;
    }
    // exp2 pre-scale (uniform per block: r,z -> log2e; n -> 2log2e)
    const float esc = (n0 < 2 * H_) ? LOG2E_F : LOG2E2_F;
#pragma unroll
    for (int mg = 0; mg < 2; mg++)
#pragma unroll
        for (int mi = 0; mi < 4; mi++) {
            const int m = m0 + mg * 64 + tm * 4 + mi;
            float* dst = gx + (size_t)m * G3_ + n0;
            float4 v0 = acc[mg][0][mi];
            v0.x = (v0.x + bb0.x) * esc; v0.y = (v0.y + bb0.y) * esc;
            v0.z = (v0.z + bb0.z) * esc; v0.w = (v0.w + bb0.w) * esc;
            float4 v1 = acc[mg][1][mi];
            v1.x = (v1.x + bb1.x) * esc; v1.y = (v1.y + bb1.y) * esc;
            v1.z = (v1.z + bb1.z) * esc; v1.w = (v1.w + bb1.w) * esc;
            *(float4*)(dst + tn * 4) = v0;
            *(float4*)(dst + 64 + tn * 4) = v1;
        }
}

// ---------------------------------------------------------------------------
// GRU recurrence U=2/K=8 + pk_fma/exp2 — R18 experiment (layer 1).
//
// Rationale: R15's pipe ledger is VALU issue 719 cyc/SIMD/step at 56% busy
// vs LDS pipe 768 cyc/step (64 ds_read_b128/CU/step x 12 cyc) — LDS is
// co-critical. U=2 halves LDS traffic (each h-read feeds 2 units' dots);
// the pk count stays 48/thread (geometry-invariant), costs only fold8x6
// (+24) and 2x gate scalar chain (+12). R13 proved this exact geometry
// (linear h2, rot=ks>>1, contiguous-8 fold8): 0 bank conflicts, exact.
//
// Thread (jg2 = tid>>3, ks = tid&7) owns units j0=2*jg2, j0+1, cols
// ks*16..+15. Reads: 4 x ds_read_b128 at ho_c = ks*16 + ((c+(ks>>1))&3)*4
// — per slot, the 8 ks-lanes hit 8 distinct bank-quads (verified: 4ks +
// (c+ks/2)&3 mod 8 is a permutation), jg2-groups broadcast. Writes (ks==0):
// float2 at even words 2*jg2 — conflict-free.
// ---------------------------------------------------------------------------
template<bool STORE_H, bool FINAL>
__global__ __launch_bounds__(512)
__attribute__((amdgpu_waves_per_eu(2, 2)))
void gru_recB(const float* __restrict__ gx,   // [B,T,384] pre-scaled, r/z incl b_hh
              const float* __restrict__ Whh,  // [384,128]
              const float* __restrict__ bhh,  // [384]
              float*       __restrict__ hseq, // [B,T,128] if STORE_H
              const float* __restrict__ fc_w, // [3,128]  if FINAL
              const float* __restrict__ fc_b, // [3]      if FINAL
              float*       __restrict__ out)  // [B,3]    if FINAL
{
    __shared__ __align__(16) float h2[2][H_];   // double-buffered h (LINEAR)

    const int tid = threadIdx.x;
    const int b   = blockIdx.x;
    const int jg2 = tid >> 3;      // unit pair 0..63
    const int ks  = tid & 7;       // k-slice 0..7 (16 cols each)
    const int j0  = jg2 * 2;       // first owned unit
    const int rot = ks >> 1;       // R13-proven bank-de-alias rotation

    // --- W fragment: rows {j0,j0+1} x {r,z,n}, cols ks*16..+15, chunks in
    // rotated order, pre-scaled for exp2 gate forms. 48 v2f = 96 floats. ---
    v2f W0r[8], W0z[8], W0n[8], W1r[8], W1z[8], W1n[8];
    {
        const float* r0 = Whh + (size_t)(j0      ) * H_ + ks * 16;
        const float* z0 = Whh + (size_t)(j0 + 128) * H_ + ks * 16;
        const float* n0 = Whh + (size_t)(j0 + 256) * H_ + ks * 16;
#pragma unroll
        for (int c = 0; c < 4; c++) {
            const int f = ((c + rot) & 3) * 4;
            v4f t;
            t = *(const v4f*)(r0 + f) * LOG2E_F;
            W0r[2 * c] = t.lo; W0r[2 * c + 1] = t.hi;
            t = *(const v4f*)(r0 + H_ + f) * LOG2E_F;
            W1r[2 * c] = t.lo; W1r[2 * c + 1] = t.hi;
            t = *(const v4f*)(z0 + f) * LOG2E_F;
            W0z[2 * c] = t.lo; W0z[2 * c + 1] = t.hi;
            t = *(const v4f*)(z0 + H_ + f) * LOG2E_F;
            W1z[2 * c] = t.lo; W1z[2 * c + 1] = t.hi;
            t = *(const v4f*)(n0 + f) * LOG2E2_F;
            W0n[2 * c] = t.lo; W0n[2 * c + 1] = t.hi;
            t = *(const v4f*)(n0 + H_ + f) * LOG2E2_F;
            W1n[2 * c] = t.lo; W1n[2 * c + 1] = t.hi;
        }
    }

    float2 bhn2 = *(const float2*)(bhh + j0 + 2 * H_);
    bhn2.x *= LOG2E2_F; bhn2.y *= LOG2E2_F;   // r,z biases folded into gx

    const float* gxb = gx + (size_t)b * T_ * G3_;
    const float* gp  = gxb + j0;
    float2 gr = *(const float2*)(gp);
    float2 gz = *(const float2*)(gp + H_);
    float2 gn = *(const float2*)(gp + 2 * H_);
    gp += G3_;
    float2 h_old; h_old.x = 0.0f; h_old.y = 0.0f;

    if (tid < H_) h2[0][tid] = 0.0f;

    // rotated read offsets (words) into the linear 128-float h buffer
    const int ho0 = ks * 16 + (((0 + rot) & 3) << 2);
    const int ho1 = ks * 16 + (((1 + rot) & 3) << 2);
    const int ho2 = ks * 16 + (((2 + rot) & 3) << 2);
    const int ho3 = ks * 16 + (((3 + rot) & 3) << 2);

    float* hp = STORE_H ? (hseq + (size_t)b * T_ * H_ + j0) : nullptr;

    __syncthreads();

#define GRU_STEPB(HIN, HOUT)                                                  \
    {                                                                         \
        const float2 gr2_ = *(const float2*)(gp);                             \
        const float2 gz2_ = *(const float2*)(gp + H_);                        \
        const float2 gn2_ = *(const float2*)(gp + 2 * H_);                    \
        gp += G3_;                                                            \
        v2f p0r = {0.f, 0.f}, p0z = {0.f, 0.f}, p0n = {0.f, 0.f};             \
        v2f p1r = {0.f, 0.f}, p1z = {0.f, 0.f}, p1n = {0.f, 0.f};             \
        {                                                                     \
            v4f hv; v2f hlo, hhi;                                             \
            hv = *(const v4f*)&(HIN)[ho0]; hlo = hv.lo; hhi = hv.hi;          \
            pk_fma(p0r, hlo, W0r[0]); pk_fma(p0r, hhi, W0r[1]);               \
            pk_fma(p0z, hlo, W0z[0]); pk_fma(p0z, hhi, W0z[1]);               \
            pk_fma(p0n, hlo, W0n[0]); pk_fma(p0n, hhi, W0n[1]);               \
            pk_fma(p1r, hlo, W1r[0]); pk_fma(p1r, hhi, W1r[1]);               \
            pk_fma(p1z, hlo, W1z[0]); pk_fma(p1z, hhi, W1z[1]);               \
            pk_fma(p1n, hlo, W1n[0]); pk_fma(p1n, hhi, W1n[1]);               \
            hv = *(const v4f*)&(HIN)[ho1]; hlo = hv.lo; hhi = hv.hi;          \
            pk_fma(p0r, hlo, W0r[2]); pk_fma(p0r, hhi, W0r[3]);               \
            pk_fma(p0z, hlo, W0z[2]); pk_fma(p0z, hhi, W0z[3]);               \
            pk_fma(p0n, hlo, W0n[2]); pk_fma(p0n, hhi, W0n[3]);               \
            pk_fma(p1r, hlo, W1r[2]); pk_fma(p1r, hhi, W1r[3]);               \
            pk_fma(p1z, hlo, W1z[2]); pk_fma(p1z, hhi, W1z[3]);               \
            pk_fma(p1n, hlo, W1n[2]); pk_fma(p1n, hhi, W1n[3]);               \
            hv = *(const v4f*)&(HIN)[ho2]; hlo = hv.lo; hhi = hv.hi;          \
            pk_fma(p0r, hlo, W0r[4]); pk_fma(p0r, hhi, W0r[5]);               \
            pk_fma(p0z, hlo, W0z[4]); pk_fma(p0z, hhi, W0z[5]);               \
            pk_fma(p0n, hlo, W0n[4]); pk_fma(p0n, hhi, W0n[5]);               \
            pk_fma(p1r, hlo, W1r[4]); pk_fma(p1r, hhi, W1r[5]);               \
            pk_fma(p1z, hlo, W1z[4]); pk_fma(p1z, hhi, W1z[5]);               \
            pk_fma(p1n, hlo, W1n[4]); pk_fma(p1n, hhi, W1n[5]);               \
            hv = *(const v4f*)&(HIN)[ho3]; hlo = hv.lo; hhi = hv.hi;          \
            pk_fma(p0r, hlo, W0r[6]); pk_fma(p0r, hhi, W0r[7]);               \
            pk_fma(p0z, hlo, W0z[6]); pk_fma(p0z, hhi, W0z[7]);               \
            pk_fma(p0n, hlo, W0n[6]); pk_fma(p0n, hhi, W0n[7]);               \
            pk_fma(p1r, hlo, W1r[6]); pk_fma(p1r, hhi, W1r[7]);               \
            pk_fma(p1z, hlo, W1z[6]); pk_fma(p1z, hhi, W1z[7]);               \
            pk_fma(p1n, hlo, W1n[6]); pk_fma(p1n, hhi, W1n[7]);               \
        }                                                                     \
        const float s0r = bfly_fold8(p0r.x + p0r.y);                          \
        const float s0z = bfly_fold8(p0z.x + p0z.y);                          \
        const float s0n = bfly_fold8(p0n.x + p0n.y);                          \
        const float s1r = bfly_fold8(p1r.x + p1r.y);                          \
        const float s1z = bfly_fold8(p1z.x + p1z.y);                          \
        const float s1n = bfly_fold8(p1n.x + p1n.y);                          \
        const float r0_ = fast_rcp(1.0f + exp2_raw(-(gr.x + s0r)));           \
        const float z0_ = fast_rcp(1.0f + exp2_raw(-(gz.x + s0z)));           \
        const float n0_ = fmaf(-2.0f,                                         \
            fast_rcp(exp2_raw(gn.x + r0_ * (s0n + bhn2.x)) + 1.0f), 1.0f);    \
        h_old.x = fmaf(z0_, h_old.x - n0_, n0_);                              \
        const float r1_ = fast_rcp(1.0f + exp2_raw(-(gr.y + s1r)));           \
        const float z1_ = fast_rcp(1.0f + exp2_raw(-(gz.y + s1z)));           \
        const float n1_ = fmaf(-2.0f,                                         \
            fast_rcp(exp2_raw(gn.y + r1_ * (s1n + bhn2.y)) + 1.0f), 1.0f);    \
        h_old.y = fmaf(z1_, h_old.y - n1_, n1_);                              \
        if (ks == 0) {                                                        \
            *(float2*)&(HOUT)[j0] = h_old;                                    \
            if (STORE_H) *(float2*)hp = h_old;                                \
        }                                                                     \
        if (STORE_H) hp += H_;                                                \
        gr = gr2_; gz = gz2_; gn = gn2_;                                      \
        __syncthreads();                                                      \
    }

    for (int t = 0; t < T_; t += 2) {
        GRU_STEPB(h2[0], h2[1])
        GRU_STEPB(h2[1], h2[0])
    }
#undef GRU_STEPB

    if (FINAL) {
        if (ks == 0) {
            h2[1][j0]     = fmaxf(h_old.x, 0.0f);
            h2[1][j0 + 1] = fmaxf(h_old.y, 0.0f);
        }
        __syncthreads();
        if (tid < 3) {
            float acc = fc_b[tid];
            const float* fw = fc_w + tid * H_;
#pragma unroll
            for (int k = 0; k < H_; k++) acc = fmaf(h2[1][k], fw[k], acc);
            out[b * 3 + tid] = acc;
        }
    }
}

// ---------------------------------------------------------------------------
// GRU recurrence K=4 — R15 kernel, UNCHANGED (A/B control, runs layer 2).
// ---------------------------------------------------------------------------
template<bool STORE_H, bool FINAL>
__global__ __launch_bounds__(512)
__attribute__((amdgpu_waves_per_eu(2, 2)))
void gru_rec(const float* __restrict__ gx,   // [B,T,384] pre-scaled, r/z incl b_hh
             const float* __restrict__ Whh,  // [384,128]
             const float* __restrict__ bhh,  // [384]
             float*       __restrict__ hseq, // [B,T,128] if STORE_H
             const float* __restrict__ fc_w, // [3,128]  if FINAL
             const float* __restrict__ fc_b, // [3]      if FINAL
             float*       __restrict__ out)  // [B,3]    if FINAL
{
    __shared__ __align__(16) float h2[2][H_];   // double-buffered swizzled h

    const int tid = threadIdx.x;
    const int b   = blockIdx.x;
    const int jg  = tid >> 2;      // hidden unit 0..127
    const int ks  = tid & 3;       // k-slice 0..3 (32 cols each)

    v2f Wr[16], Wz[16], Wn[16];
    {
        const v4f* wr = (const v4f*)(Whh + (size_t)(jg      ) * H_ + ks * 32);
        const v4f* wz = (const v4f*)(Whh + (size_t)(jg + 128) * H_ + ks * 32);
        const v4f* wn = (const v4f*)(Whh + (size_t)(jg + 256) * H_ + ks * 32);
#pragma unroll
        for (int c = 0; c < 8; c++) {
            v4f t;
            t = wr[c] * LOG2E_F;  Wr[2 * c] = t.lo; Wr[2 * c + 1] = t.hi;
            t = wz[c] * LOG2E_F;  Wz[2 * c] = t.lo; Wz[2 * c + 1] = t.hi;
            t = wn[c] * LOG2E2_F; Wn[2 * c] = t.lo; Wn[2 * c + 1] = t.hi;
        }
    }

    const float bhn = bhh[jg + 2 * H_] * LOG2E2_F;

    const float* gxb = gx + (size_t)b * T_ * G3_;
    float gr = gxb[jg], gz = gxb[jg + 128], gn = gxb[jg + 256];
    float h_old = 0.0f;

    if (tid < H_) h2[0][tid] = 0.0f;

    const int hw = ((jg >> 2) & 7) * 16 + (jg >> 5) * 4 + (jg & 3);
    const int hb = ks * 4;

    const float* gnx = gxb + G3_;
    float* hp = STORE_H ? (hseq + (size_t)b * T_ * H_ + jg) : nullptr;

    __syncthreads();

#define GRU_STEP(HIN, HOUT)                                                   \
    {                                                                         \
        const float gr2_ = gnx[jg];                                           \
        const float gz2_ = gnx[jg + 128];                                     \
        const float gn2_ = gnx[jg + 256];                                     \
        gnx += G3_;                                                           \
        v2f pr = {0.f, 0.f}, pz = {0.f, 0.f}, pn = {0.f, 0.f};                \
        _Pragma("unroll")                                                     \
        for (int c = 0; c < 8; c++) {                                         \
            v4f hv = *(const v4f*)&(HIN)[16 * c + hb];                        \
            v2f hlo = hv.lo, hhi = hv.hi;                                     \
            pk_fma(pr, hlo, Wr[2 * c]);  pk_fma(pr, hhi, Wr[2 * c + 1]);      \
            pk_fma(pz, hlo, Wz[2 * c]);  pk_fma(pz, hhi, Wz[2 * c + 1]);      \
            pk_fma(pn, hlo, Wn[2 * c]);  pk_fma(pn, hhi, Wn[2 * c + 1]);      \
        }                                                                     \
        const float p0 = bfly_fold4(pr.x + pr.y);                             \
        const float p1 = bfly_fold4(pz.x + pz.y);                             \
        const float p2 = bfly_fold4(pn.x + pn.y);                             \
        const float r_ = fast_rcp(1.0f + exp2_raw(-(gr + p0)));               \
        const float z_ = fast_rcp(1.0f + exp2_raw(-(gz + p1)));               \
        const float n_ = fmaf(-2.0f,                                          \
            fast_rcp(exp2_raw(gn + r_ * (p2 + bhn)) + 1.0f), 1.0f);           \
        h_old = fmaf(z_, h_old - n_, n_);                                     \
        if (ks == 0) {                                                        \
            (HOUT)[hw] = h_old;                                               \
            if (STORE_H) *hp = h_old;                                         \
        }                                                                     \
        if (STORE_H) hp += H_;                                                \
        gr = gr2_; gz = gz2_; gn = gn2_;                                      \
        __syncthreads();                                                      \
    }

    for (int t = 0; t < T_; t += 2) {
        GRU_STEP(h2[0], h2[1])
        GRU_STEP(h2[1], h2[0])
    }
#undef GRU_STEP

    if (FINAL) {
        if (ks == 0) h2[1][jg] = fmaxf(h_old, 0.0f);
        __syncthreads();
        if (tid < 3) {
            float acc = fc_b[tid];
            const float* fw = fc_w + tid * H_;
#pragma unroll
            for (int k = 0; k < H_; k++) acc = fmaf(h2[1][k], fw[k], acc);
            out[b * 3 + tid] = acc;
        }
    }
}

// ---------------------------------------------------------------------------
extern "C" void kernel_launch(void* const* d_in, const int* in_sizes, int n_in,
                              void* d_out, int out_size, void* d_ws, size_t ws_size,
                              hipStream_t stream)
{
    const int*   x    = (const int*)  d_in[0];
    const float* emb  = (const float*)d_in[1];
    const float* W_ih = (const float*)d_in[2];  // [2,384,128]
    const float* W_hh = (const float*)d_in[3];  // [2,384,128]
    const float* b_ih = (const float*)d_in[4];  // [2,384]
    const float* b_hh = (const float*)d_in[5];  // [2,384]
    const float* fc_w = (const float*)d_in[6];  // [3,128]
    const float* fc_b = (const float*)d_in[7];  // [3]
    float* out = (float*)d_out;

    const int M = B_ * T_;                                   // 131072 rows
    const size_t gx_f32 = (size_t)M * G3_ * sizeof(float);   // 201.3 MB

    float* gx = (float*)d_ws;
    float* h1 = (float*)((char*)d_ws + gx_f32);              // 67.1 MB

    dim3 ggx(G3_ / TN, M / TM);   // (3, 1024)
    dim3 bgx(256);
    dim3 grec(B_), brec(512);

    hipLaunchKernelGGL((gx_gemm<true>), ggx, bgx, 0, stream,
                       nullptr, x, emb, W_ih, b_ih, b_hh, gx);
    // A/B: layer 1 = U=2/K=8 + pk_fma/exp2 (halved LDS-pipe load)
    hipLaunchKernelGGL((gru_recB<true, false>), grec, brec, 0, stream,
                       gx, W_hh, b_hh, h1, nullptr, nullptr, nullptr);
    hipLaunchKernelGGL((gx_gemm<false>), ggx, bgx, 0, stream,
                       h1, nullptr, nullptr, W_ih + G3_ * H_, b_ih + G3_,
                       b_hh + G3_, gx);
    // control: layer 2 = R15 K=4 kernel unchanged
    hipLaunchKernelGGL((gru_rec<false, true>), grec, brec, 0, stream,
                       gx, W_hh + G3_ * H_, b_hh + G3_, nullptr, fc_w, fc_b, out);
}

// Round 12
// 929.052 us; speedup vs baseline: 1.0325x; 1.0325x over previous
//
#include <hip/hip_runtime.h>
#include <hip/hip_bf16.h>

#define B_   256
#define T_   512
#define H_   128
#define G3_  384

// ---- tiled GEMM config ----
#define TM   128
#define TN   128
#define TK   32
#define LDA  132

// log2(e) and 2*log2(e): gate pre-activations are pre-scaled so the serial
// recurrence uses raw v_exp_f32 (2^x) with no per-call *1.4427 mul.
#define LOG2E_F  1.4426950408889634f
#define LOG2E2_F 2.8853900817779268f

typedef float v4f __attribute__((ext_vector_type(4)));
typedef float v2f __attribute__((ext_vector_type(2)));

__device__ __forceinline__ float fast_rcp(float x) {
    return __builtin_amdgcn_rcpf(x);
}
__device__ __forceinline__ float exp2_raw(float x) {
    return __builtin_amdgcn_exp2f(x);   // v_exp_f32: 2^x
}

// Packed FMA, all operands arch-VGPR (R15-proven; VOP3P cannot take AGPR
// sources on gfx950 — R17 compile falsifier).
__device__ __forceinline__ void pk_fma(v2f& acc, v2f a, v2f b) {
    asm("v_pk_fma_f32 %0, %1, %2, %0" : "+v"(acc) : "v"(a), "v"(b));
}

// Butterfly sum over each aligned 4-lane quad, pure DPP, result on ALL lanes.
__device__ __forceinline__ float bfly_fold4(float v) {
    int x;
    x = __builtin_amdgcn_update_dpp(0, __float_as_int(v), 0x0B1, 0xF, 0xF, true);
    v += __int_as_float(x);   // xor 1
    x = __builtin_amdgcn_update_dpp(0, __float_as_int(v), 0x04E, 0xF, 0xF, true);
    v += __int_as_float(x);   // xor 2
    return v;
}

// R19 relaxed barrier: __syncthreads() emits s_waitcnt vmcnt(0) lgkmcnt(0)
// before s_barrier (m97 lesson) — draining our per-step global prefetch
// loads and hseq stores into EVERY step (~100-250 cyc exposed latency).
// Correctness only needs LDS ordering (h-writes visible before next-step
// reads): drain lgkmcnt only. Global loads keep compiler vmcnt waits at
// their USE; stores drain at kernel end. "memory" fences stop reordering
// across the barrier (guide rule #18).
__device__ __forceinline__ void lds_barrier() {
    asm volatile("s_waitcnt lgkmcnt(0)" ::: "memory");
    __builtin_amdgcn_s_barrier();
    asm volatile("" ::: "memory");
}

// ---------------------------------------------------------------------------
// gx GEMM (R2 structure; R14 bias2 fold; R15 exp2 pre-scale epilogue)
// ---------------------------------------------------------------------------
template<bool GATHER>
__global__ __launch_bounds__(256, 2)
void gx_gemm(const float* __restrict__ X,
             const int*   __restrict__ idx,
             const float* __restrict__ emb,
             const float* __restrict__ W,     // [384,128] row-major
             const float* __restrict__ bias,  // [384]  (b_ih)
             const float* __restrict__ bias2, // [384]  (b_hh; only n<256 used)
             float*       __restrict__ gx)    // [M,384]
{
    __shared__ __align__(16) float As[2][TK][LDA];
    __shared__ __align__(16) float Bs[2][TK][LDA];

    const int tid = threadIdx.x;
    const int tn  = tid & 15;
    const int tm  = tid >> 4;
    const int n0  = blockIdx.x * TN;
    const int m0  = blockIdx.y * TM;

    const int q  = tid & 7;
    const float* rowA[4];
    const float* rowB[4];
#pragma unroll
    for (int s = 0; s < 4; s++) {
        const int r = (tid >> 3) + 32 * s;
        rowA[s] = GATHER ? (emb + (size_t)idx[m0 + r] * H_)
                         : (X + (size_t)(m0 + r) * H_);
        rowB[s] = W + (size_t)(n0 + r) * H_;
    }

    float4 stA[4], stB[4];
    auto load_chunk = [&](int kc) {
#pragma unroll
        for (int s = 0; s < 4; s++) {
            stA[s] = *(const float4*)(rowA[s] + kc + q * 4);
            stB[s] = *(const float4*)(rowB[s] + kc + q * 4);
        }
    };
    auto store_chunk = [&](int buf) {
#pragma unroll
        for (int s = 0; s < 4; s++) {
            const int r = (tid >> 3) + 32 * s;
#pragma unroll
            for (int d = 0; d < 4; d++) {
                As[buf][q * 4 + d][r] = ((const float*)&stA[s])[d];
                Bs[buf][q * 4 + d][r] = ((const float*)&stB[s])[d];
            }
        }
    };

    float4 acc[2][2][4];
#pragma unroll
    for (int a = 0; a < 2; a++)
#pragma unroll
        for (int b = 0; b < 2; b++)
#pragma unroll
            for (int c = 0; c < 4; c++) acc[a][b][c] = make_float4(0.f, 0.f, 0.f, 0.f);

    load_chunk(0);
    store_chunk(0);
    __syncthreads();

    for (int c = 0; c < 4; c++) {
        if (c < 3) load_chunk((c + 1) * TK);
        const int buf = c & 1;
#pragma unroll 4
        for (int k = 0; k < TK; k++) {
            float4 a0 = *(const float4*)&As[buf][k][tm * 4];
            float4 a1 = *(const float4*)&As[buf][k][64 + tm * 4];
            float4 b0 = *(const float4*)&Bs[buf][k][tn * 4];
            float4 b1 = *(const float4*)&Bs[buf][k][64 + tn * 4];
            float4 av[2] = {a0, a1}, bv[2] = {b0, b1};
#pragma unroll
            for (int mg = 0; mg < 2; mg++)
#pragma unroll
                for (int mi = 0; mi < 4; mi++) {
                    const float am = ((const float*)&av[mg])[mi];
#pragma unroll
                    for (int ng = 0; ng < 2; ng++) {
                        acc[mg][ng][mi].x = fmaf(am, bv[ng].x, acc[mg][ng][mi].x);
                        acc[mg][ng][mi].y = fmaf(am, bv[ng].y, acc[mg][ng][mi].y);
                        acc[mg][ng][mi].z = fmaf(am, bv[ng].z, acc[mg][ng][mi].z);
                        acc[mg][ng][mi].w = fmaf(am, bv[ng].w, acc[mg][ng][mi].w);
                    }
                }
        }
        if (c < 3) {
            store_chunk(buf ^ 1);
            __syncthreads();
        }
    }

    float4 bb0 = *(const float4*)(bias + n0 + tn * 4);
    float4 bb1 = *(const float4*)(bias + n0 + 64 + tn * 4);
    if (n0 < 2 * H_) {   // r/z gate regions: fold hidden bias in here (uniform)
        const float4 c0 = *(const float4*)(bias2 + n0 + tn * 4);
        const float4 c1 = *(const float4*)(bias2 + n0 + 64 + tn * 4);
        bb0.x += c0.x; bb0.y += c0.y; bb0.z += c0.z; bb0.w += c0.w;
        bb1.x += c1.x; bb1.y += c1.y; bb1.z += c1.z; bb1.w += c1.w;
    }
    // exp2 pre-scale (uniform per block: r,z -> log2e; n -> 2log2e)
    const float esc = (n0 < 2 * H_) ? LOG2E_F : LOG2E2_F;
#pragma unroll
    for (int mg = 0; mg < 2; mg++)
#pragma unroll
        for (int mi = 0; mi < 4; mi++) {
            const int m = m0 + mg * 64 + tm * 4 + mi;
            float* dst = gx + (size_t)m * G3_ + n0;
            float4 v0 = acc[mg][0][mi];
            v0.x = (v0.x + bb0.x) * esc; v0.y = (v0.y + bb0.y) * esc;
            v0.z = (v0.z + bb0.z) * esc; v0.w = (v0.w + bb0.w) * esc;
            float4 v1 = acc[mg][1][mi];
            v1.x = (v1.x + bb1.x) * esc; v1.y = (v1.y + bb1.y) * esc;
            v1.z = (v1.z + bb1.z) * esc; v1.w = (v1.w + bb1.w) * esc;
            *(float4*)(dst + tn * 4) = v0;
            *(float4*)(dst + 64 + tn * 4) = v1;
        }
}

// ---------------------------------------------------------------------------
// GRU recurrence K=4, RELAXED BARRIER — R19 experiment (layer 1).
// Identical to the R15 control below except the per-step __syncthreads()
// is replaced by lds_barrier() (lgkmcnt-only drain, no vmcnt(0)).
// ---------------------------------------------------------------------------
template<bool STORE_H, bool FINAL>
__global__ __launch_bounds__(512)
__attribute__((amdgpu_waves_per_eu(2, 2)))
void gru_recC(const float* __restrict__ gx,   // [B,T,384] pre-scaled, r/z incl b_hh
              const float* __restrict__ Whh,  // [384,128]
              const float* __restrict__ bhh,  // [384]
              float*       __restrict__ hseq, // [B,T,128] if STORE_H
              const float* __restrict__ fc_w, // [3,128]  if FINAL
              const float* __restrict__ fc_b, // [3]      if FINAL
              float*       __restrict__ out)  // [B,3]    if FINAL
{
    __shared__ __align__(16) float h2[2][H_];   // double-buffered swizzled h

    const int tid = threadIdx.x;
    const int b   = blockIdx.x;
    const int jg  = tid >> 2;      // hidden unit 0..127
    const int ks  = tid & 3;       // k-slice 0..3 (32 cols each)

    v2f Wr[16], Wz[16], Wn[16];
    {
        const v4f* wr = (const v4f*)(Whh + (size_t)(jg      ) * H_ + ks * 32);
        const v4f* wz = (const v4f*)(Whh + (size_t)(jg + 128) * H_ + ks * 32);
        const v4f* wn = (const v4f*)(Whh + (size_t)(jg + 256) * H_ + ks * 32);
#pragma unroll
        for (int c = 0; c < 8; c++) {
            v4f t;
            t = wr[c] * LOG2E_F;  Wr[2 * c] = t.lo; Wr[2 * c + 1] = t.hi;
            t = wz[c] * LOG2E_F;  Wz[2 * c] = t.lo; Wz[2 * c + 1] = t.hi;
            t = wn[c] * LOG2E2_F; Wn[2 * c] = t.lo; Wn[2 * c + 1] = t.hi;
        }
    }

    const float bhn = bhh[jg + 2 * H_] * LOG2E2_F;

    const float* gxb = gx + (size_t)b * T_ * G3_;
    float gr = gxb[jg], gz = gxb[jg + 128], gn = gxb[jg + 256];
    float h_old = 0.0f;

    if (tid < H_) h2[0][tid] = 0.0f;

    const int hw = ((jg >> 2) & 7) * 16 + (jg >> 5) * 4 + (jg & 3);
    const int hb = ks * 4;

    const float* gnx = gxb + G3_;
    float* hp = STORE_H ? (hseq + (size_t)b * T_ * H_ + jg) : nullptr;

    __syncthreads();

#define GRU_STEPC(HIN, HOUT)                                                  \
    {                                                                         \
        const float gr2_ = gnx[jg];                                           \
        const float gz2_ = gnx[jg + 128];                                     \
        const float gn2_ = gnx[jg + 256];                                     \
        gnx += G3_;                                                           \
        v2f pr = {0.f, 0.f}, pz = {0.f, 0.f}, pn = {0.f, 0.f};                \
        _Pragma("unroll")                                                     \
        for (int c = 0; c < 8; c++) {                                         \
            v4f hv = *(const v4f*)&(HIN)[16 * c + hb];                        \
            v2f hlo = hv.lo, hhi = hv.hi;                                     \
            pk_fma(pr, hlo, Wr[2 * c]);  pk_fma(pr, hhi, Wr[2 * c + 1]);      \
            pk_fma(pz, hlo, Wz[2 * c]);  pk_fma(pz, hhi, Wz[2 * c + 1]);      \
            pk_fma(pn, hlo, Wn[2 * c]);  pk_fma(pn, hhi, Wn[2 * c + 1]);      \
        }                                                                     \
        const float p0 = bfly_fold4(pr.x + pr.y);                             \
        const float p1 = bfly_fold4(pz.x + pz.y);                             \
        const float p2 = bfly_fold4(pn.x + pn.y);                             \
        const float r_ = fast_rcp(1.0f + exp2_raw(-(gr + p0)));               \
        const float z_ = fast_rcp(1.0f + exp2_raw(-(gz + p1)));               \
        const float n_ = fmaf(-2.0f,                                          \
            fast_rcp(exp2_raw(gn + r_ * (p2 + bhn)) + 1.0f), 1.0f);           \
        h_old = fmaf(z_, h_old - n_, n_);                                     \
        if (ks == 0) {                                                        \
            (HOUT)[hw] = h_old;                                               \
            if (STORE_H) *hp = h_old;                                         \
        }                                                                     \
        if (STORE_H) hp += H_;                                                \
        gr = gr2_; gz = gz2_; gn = gn2_;                                      \
        lds_barrier();                                                        \
    }

    for (int t = 0; t < T_; t += 2) {
        GRU_STEPC(h2[0], h2[1])
        GRU_STEPC(h2[1], h2[0])
    }
#undef GRU_STEPC

    if (FINAL) {
        if (ks == 0) h2[1][jg] = fmaxf(h_old, 0.0f);
        __syncthreads();
        if (tid < 3) {
            float acc = fc_b[tid];
            const float* fw = fc_w + tid * H_;
#pragma unroll
            for (int k = 0; k < H_; k++) acc = fmaf(h2[1][k], fw[k], acc);
            out[b * 3 + tid] = acc;
        }
    }
}

// ---------------------------------------------------------------------------
// GRU recurrence K=4 — R15 kernel, UNCHANGED (A/B control, runs layer 2).
// ---------------------------------------------------------------------------
template<bool STORE_H, bool FINAL>
__global__ __launch_bounds__(512)
__attribute__((amdgpu_waves_per_eu(2, 2)))
void gru_rec(const float* __restrict__ gx,   // [B,T,384] pre-scaled, r/z incl b_hh
             const float* __restrict__ Whh,  // [384,128]
             const float* __restrict__ bhh,  // [384]
             float*       __restrict__ hseq, // [B,T,128] if STORE_H
             const float* __restrict__ fc_w, // [3,128]  if FINAL
             const float* __restrict__ fc_b, // [3]      if FINAL
             float*       __restrict__ out)  // [B,3]    if FINAL
{
    __shared__ __align__(16) float h2[2][H_];   // double-buffered swizzled h

    const int tid = threadIdx.x;
    const int b   = blockIdx.x;
    const int jg  = tid >> 2;      // hidden unit 0..127
    const int ks  = tid & 3;       // k-slice 0..3 (32 cols each)

    v2f Wr[16], Wz[16], Wn[16];
    {
        const v4f* wr = (const v4f*)(Whh + (size_t)(jg      ) * H_ + ks * 32);
        const v4f* wz = (const v4f*)(Whh + (size_t)(jg + 128) * H_ + ks * 32);
        const v4f* wn = (const v4f*)(Whh + (size_t)(jg + 256) * H_ + ks * 32);
#pragma unroll
        for (int c = 0; c < 8; c++) {
            v4f t;
            t = wr[c] * LOG2E_F;  Wr[2 * c] = t.lo; Wr[2 * c + 1] = t.hi;
            t = wz[c] * LOG2E_F;  Wz[2 * c] = t.lo; Wz[2 * c + 1] = t.hi;
            t = wn[c] * LOG2E2_F; Wn[2 * c] = t.lo; Wn[2 * c + 1] = t.hi;
        }
    }

    const float bhn = bhh[jg + 2 * H_] * LOG2E2_F;

    const float* gxb = gx + (size_t)b * T_ * G3_;
    float gr = gxb[jg], gz = gxb[jg + 128], gn = gxb[jg + 256];
    float h_old = 0.0f;

    if (tid < H_) h2[0][tid] = 0.0f;

    const int hw = ((jg >> 2) & 7) * 16 + (jg >> 5) * 4 + (jg & 3);
    const int hb = ks * 4;

    const float* gnx = gxb + G3_;
    float* hp = STORE_H ? (hseq + (size_t)b * T_ * H_ + jg) : nullptr;

    __syncthreads();

#define GRU_STEP(HIN, HOUT)                                                   \
    {                                                                         \
        const float gr2_ = gnx[jg];                                           \
        const float gz2_ = gnx[jg + 128];                                     \
        const float gn2_ = gnx[jg + 256];                                     \
        gnx += G3_;                                                           \
        v2f pr = {0.f, 0.f}, pz = {0.f, 0.f}, pn = {0.f, 0.f};                \
        _Pragma("unroll")                                                     \
        for (int c = 0; c < 8; c++) {                                         \
            v4f hv = *(const v4f*)&(HIN)[16 * c + hb];                        \
            v2f hlo = hv.lo, hhi = hv.hi;                                     \
            pk_fma(pr, hlo, Wr[2 * c]);  pk_fma(pr, hhi, Wr[2 * c + 1]);      \
            pk_fma(pz, hlo, Wz[2 * c]);  pk_fma(pz, hhi, Wz[2 * c + 1]);      \
            pk_fma(pn, hlo, Wn[2 * c]);  pk_fma(pn, hhi, Wn[2 * c + 1]);      \
        }                                                                     \
        const float p0 = bfly_fold4(pr.x + pr.y);                             \
        const float p1 = bfly_fold4(pz.x + pz.y);                             \
        const float p2 = bfly_fold4(pn.x + pn.y);                             \
        const float r_ = fast_rcp(1.0f + exp2_raw(-(gr + p0)));               \
        const float z_ = fast_rcp(1.0f + exp2_raw(-(gz + p1)));               \
        const float n_ = fmaf(-2.0f,                                          \
            fast_rcp(exp2_raw(gn + r_ * (p2 + bhn)) + 1.0f), 1.0f);           \
        h_old = fmaf(z_, h_old - n_, n_);                                     \
        if (ks == 0) {                                                        \
            (HOUT)[hw] = h_old;                                               \
            if (STORE_H) *hp = h_old;                                         \
        }                                                                     \
        if (STORE_H) hp += H_;                                                \
        gr = gr2_; gz = gz2_; gn = gn2_;                                      \
        __syncthreads();                                                      \
    }

    for (int t = 0; t < T_; t += 2) {
        GRU_STEP(h2[0], h2[1])
        GRU_STEP(h2[1], h2[0])
    }
#undef GRU_STEP

    if (FINAL) {
        if (ks == 0) h2[1][jg] = fmaxf(h_old, 0.0f);
        __syncthreads();
        if (tid < 3) {
            float acc = fc_b[tid];
            const float* fw = fc_w + tid * H_;
#pragma unroll
            for (int k = 0; k < H_; k++) acc = fmaf(h2[1][k], fw[k], acc);
            out[b * 3 + tid] = acc;
        }
    }
}

// ---------------------------------------------------------------------------
extern "C" void kernel_launch(void* const* d_in, const int* in_sizes, int n_in,
                              void* d_out, int out_size, void* d_ws, size_t ws_size,
                              hipStream_t stream)
{
    const int*   x    = (const int*)  d_in[0];
    const float* emb  = (const float*)d_in[1];
    const float* W_ih = (const float*)d_in[2];  // [2,384,128]
    const float* W_hh = (const float*)d_in[3];  // [2,384,128]
    const float* b_ih = (const float*)d_in[4];  // [2,384]
    const float* b_hh = (const float*)d_in[5];  // [2,384]
    const float* fc_w = (const float*)d_in[6];  // [3,128]
    const float* fc_b = (const float*)d_in[7];  // [3]
    float* out = (float*)d_out;

    const int M = B_ * T_;                                   // 131072 rows
    const size_t gx_f32 = (size_t)M * G3_ * sizeof(float);   // 201.3 MB

    float* gx = (float*)d_ws;
    float* h1 = (float*)((char*)d_ws + gx_f32);              // 67.1 MB

    dim3 ggx(G3_ / TN, M / TM);   // (3, 1024)
    dim3 bgx(256);
    dim3 grec(B_), brec(512);

    hipLaunchKernelGGL((gx_gemm<true>), ggx, bgx, 0, stream,
                       nullptr, x, emb, W_ih, b_ih, b_hh, gx);
    // A/B: layer 1 = relaxed (lgkmcnt-only) per-step barrier
    hipLaunchKernelGGL((gru_recC<true, false>), grec, brec, 0, stream,
                       gx, W_hh, b_hh, h1, nullptr, nullptr, nullptr);
    hipLaunchKernelGGL((gx_gemm<false>), ggx, bgx, 0, stream,
                       h1, nullptr, nullptr, W_ih + G3_ * H_, b_ih + G3_,
                       b_hh + G3_, gx);
    // control: layer 2 = R15 K=4 kernel unchanged (__syncthreads barrier)
    hipLaunchKernelGGL((gru_rec<false, true>), grec, brec, 0, stream,
                       gx, W_hh + G3_ * H_, b_hh + G3_, nullptr, fc_w, fc_b, out);
}